// Round 2
// baseline (3162.457 us; speedup 1.0000x reference)
//
#include <hip/hip_runtime.h>
#include <hip/hip_bf16.h>

#define NN 16384
#define DD 128
#define KP1 11
#define NSPLIT 8
#define RBLK 256
#define CBLK 64
#define COLS_PER_SPLIT (NN / NSPLIT)   /* 2048 */
#define NITER (COLS_PER_SPLIT / CBLK)  /* 32 */

typedef __attribute__((ext_vector_type(8))) short bf16x8;
typedef __attribute__((ext_vector_type(4))) float f32x4;

// ---------------------------------------------------------------------------
// Phase A: proj = feat @ W^T (fp32 exact), row L2 norm, bf16 normalized copy
// ---------------------------------------------------------------------------
__global__ __launch_bounds__(256) void phaseA_kernel(
    const float* __restrict__ feat, const float* __restrict__ W,
    float* __restrict__ proj, __hip_bfloat16* __restrict__ nrmb) {
  __shared__ float Wl[DD][132];   // pad 132: 16B-aligned rows, spread banks
  __shared__ float fl[16][DD];
  const int t = threadIdx.x;
  const int blk = blockIdx.x;     // 16 rows per block

  // stage W: 16384 floats = 4096 float4
  const f32x4* W4 = (const f32x4*)W;
#pragma unroll
  for (int i = 0; i < 16; ++i) {
    int f4 = t + 256 * i;
    *(f32x4*)&Wl[f4 >> 5][(f4 & 31) * 4] = W4[f4];
  }
  // stage 16 feat rows: 2048 floats = 512 float4
  const f32x4* F4 = (const f32x4*)(feat + (size_t)blk * 16 * DD);
#pragma unroll
  for (int i = 0; i < 2; ++i) {
    int f4 = t + 256 * i;
    *(f32x4*)&fl[f4 >> 5][(f4 & 31) * 4] = F4[f4];
  }
  __syncthreads();

  const int w = t >> 6, l = t & 63;
#pragma unroll 1
  for (int q = 0; q < 4; ++q) {
    const int rloc = w * 4 + q;
    const int r = blk * 16 + rloc;
    float a0 = 0.f, a1 = 0.f;
#pragma unroll
    for (int k = 0; k < DD; k += 4) {
      f32x4 fv = *(const f32x4*)&fl[rloc][k];
      f32x4 w0 = *(const f32x4*)&Wl[l][k];
      f32x4 w1 = *(const f32x4*)&Wl[l + 64][k];
      a0 += fv[0] * w0[0] + fv[1] * w0[1] + fv[2] * w0[2] + fv[3] * w0[3];
      a1 += fv[0] * w1[0] + fv[1] * w1[1] + fv[2] * w1[2] + fv[3] * w1[3];
    }
    float n2 = a0 * a0 + a1 * a1;
#pragma unroll
    for (int o = 32; o > 0; o >>= 1) n2 += __shfl_xor(n2, o);
    float invn = 1.0f / fmaxf(sqrtf(n2), 1e-12f);
    proj[(size_t)r * DD + l] = a0;
    proj[(size_t)r * DD + l + 64] = a1;
    nrmb[(size_t)r * DD + l] = __float2bfloat16(a0 * invn);
    nrmb[(size_t)r * DD + l + 64] = __float2bfloat16(a1 * invn);
  }
}

// ---------------------------------------------------------------------------
// Phase B: tiled Gram matrix via bf16 MFMA + fused per-row top-11
// grid = 64 row-blocks x 8 col-splits; block = 256 thr (4 waves)
// ---------------------------------------------------------------------------
#define INSERT11(vv, cc)                                                   \
  if ((vv) > tv[KP1 - 1]) {                                                \
    float pv_ = (vv); int pc_ = (cc);                                      \
    _Pragma("unroll")                                                      \
    for (int p_ = 0; p_ < KP1; ++p_) {                                     \
      bool take_ = pv_ > tv[p_];                                           \
      float ov_ = tv[p_]; int oc_ = ti[p_];                                \
      if (take_) { tv[p_] = pv_; ti[p_] = pc_; pv_ = ov_; pc_ = oc_; }     \
    }                                                                      \
  }

__global__ __launch_bounds__(256) void phaseB_kernel(
    const __hip_bfloat16* __restrict__ nrmb,
    float* __restrict__ tkv, int* __restrict__ tki) {
  __shared__ __hip_bfloat16 Bt[CBLK][136];  // 64x136x2B, 16B-aligned rows
  __shared__ float Sm[RBLK][68];            // 256x68x4B, 16B-aligned rows
  const int t = threadIdx.x;
  const int w = t >> 6, l = t & 63;
  const int rb = blockIdx.x & 63;
  const int cs = blockIdx.x >> 6;
  const int row0 = rb * RBLK;
  const int wrow = row0 + w * 64;
  const int lr = l & 15, lg = l >> 4;

  // A fragments held in registers for the whole kernel: 4 row-subtiles x 4 k
  bf16x8 A[4][4];
#pragma unroll
  for (int rt = 0; rt < 4; ++rt)
#pragma unroll
    for (int kt = 0; kt < 4; ++kt)
      A[rt][kt] = *(const bf16x8*)((const unsigned short*)nrmb +
                    (size_t)(wrow + rt * 16 + lr) * DD + kt * 32 + lg * 8);

  float tv[KP1]; int ti[KP1];
#pragma unroll
  for (int i = 0; i < KP1; ++i) { tv[i] = -3.0e38f; ti[i] = -1; }

  const int csbase = cs * COLS_PER_SPLIT;

  for (int it = 0; it < NITER; ++it) {
    // stage B tile (64 candidate rows x 128 bf16)
    {
      const int rr = t >> 2, ch = t & 3;
      const unsigned short* src =
          (const unsigned short*)nrmb + (size_t)(csbase + it * CBLK + rr) * DD + ch * 32;
#pragma unroll
      for (int p = 0; p < 4; ++p)
        *(bf16x8*)&Bt[rr][ch * 32 + p * 8] = *(const bf16x8*)(src + p * 8);
    }
    // scan previous sims tile (overlaps staging; both precede the barrier)
    if (it > 0) {
      const int cprev = csbase + (it - 1) * CBLK;
#pragma unroll
      for (int j4 = 0; j4 < 16; ++j4) {
        f32x4 v = *(const f32x4*)&Sm[t][j4 * 4];
#pragma unroll
        for (int u = 0; u < 4; ++u) {
          float vv = v[u];
          INSERT11(vv, cprev + j4 * 4 + u);
        }
      }
    }
    __syncthreads();
    // MFMA: 64x64 sims per wave, write to LDS in C/D layout
#pragma unroll
    for (int ct2 = 0; ct2 < 4; ++ct2) {
      bf16x8 B[4];
#pragma unroll
      for (int kt = 0; kt < 4; ++kt)
        B[kt] = *(const bf16x8*)&Bt[ct2 * 16 + lr][kt * 32 + lg * 8];
      f32x4 acc[4];
#pragma unroll
      for (int rt = 0; rt < 4; ++rt) acc[rt] = (f32x4){0.f, 0.f, 0.f, 0.f};
#pragma unroll
      for (int kt = 0; kt < 4; ++kt)
#pragma unroll
        for (int rt = 0; rt < 4; ++rt)
          acc[rt] = __builtin_amdgcn_mfma_f32_16x16x32_bf16(A[rt][kt], B[kt], acc[rt], 0, 0, 0);
#pragma unroll
      for (int rt = 0; rt < 4; ++rt)
#pragma unroll
        for (int i = 0; i < 4; ++i)
          Sm[w * 64 + rt * 16 + lg * 4 + i][ct2 * 16 + lr] = acc[rt][i];
    }
    __syncthreads();
  }
  // final tile scan
  {
    const int cprev = csbase + (NITER - 1) * CBLK;
#pragma unroll
    for (int j4 = 0; j4 < 16; ++j4) {
      f32x4 v = *(const f32x4*)&Sm[t][j4 * 4];
#pragma unroll
      for (int u = 0; u < 4; ++u) {
        float vv = v[u];
        INSERT11(vv, cprev + j4 * 4 + u);
      }
    }
  }
  const int myrow = row0 + t;
  float* ov = tkv + ((size_t)cs * NN + myrow) * KP1;
  int* oi = tki + ((size_t)cs * NN + myrow) * KP1;
#pragma unroll
  for (int i = 0; i < KP1; ++i) { ov[i] = tv[i]; oi[i] = ti[i]; }
}

// ---------------------------------------------------------------------------
// Phase C: merge 8x11 partial top-k per row, softmax (self masked), gather
// one wave per row; 4 rows per 256-thread block. fp32 output.
// ---------------------------------------------------------------------------
__global__ __launch_bounds__(256) void phaseC_kernel(
    const float* __restrict__ proj, const float* __restrict__ feat,
    const float* __restrict__ emb, const float* __restrict__ tkv,
    const int* __restrict__ tki, float* __restrict__ out) {
  const int t = threadIdx.x, w = t >> 6, l = t & 63;
  const int r = blockIdx.x * 4 + w;

  // 88 candidates: slot0 = lane (0..63), slot1 = 64+lane (lanes 0..23)
  float v0, v1 = -3.0e38f;
  int i0, i1 = 0x7fffffff;
  {
    int j = l, s = j / KP1, k = j - s * KP1;
    v0 = tkv[((size_t)s * NN + r) * KP1 + k];
    i0 = tki[((size_t)s * NN + r) * KP1 + k];
  }
  if (l < 88 - 64) {
    int j = 64 + l, s = j / KP1, k = j - s * KP1;
    v1 = tkv[((size_t)s * NN + r) * KP1 + k];
    i1 = tki[((size_t)s * NN + r) * KP1 + k];
  }

  bool t0 = false, t1 = false;
  float selv[KP1]; int seli[KP1];
#pragma unroll
  for (int s = 0; s < KP1; ++s) {
    float bv = -3.0e38f; int bi = 0x7fffffff;
    if (!t0 && (v0 > bv || (v0 == bv && i0 < bi))) { bv = v0; bi = i0; }
    if (!t1 && (v1 > bv || (v1 == bv && i1 < bi))) { bv = v1; bi = i1; }
#pragma unroll
    for (int o = 32; o > 0; o >>= 1) {
      float ovv = __shfl_xor(bv, o);
      int obi = __shfl_xor(bi, o);
      if (ovv > bv || (ovv == bv && obi < bi)) { bv = ovv; bi = obi; }
    }
    selv[s] = bv; seli[s] = bi;
    if (!t0 && i0 == bi) t0 = true;
    else if (!t1 && i1 == bi) t1 = true;
  }

  float m = -3.0e38f;
#pragma unroll
  for (int s = 0; s < KP1; ++s)
    if (seli[s] != r) m = fmaxf(m, selv[s]);
  float den = 0.f; float wg[KP1];
#pragma unroll
  for (int s = 0; s < KP1; ++s) {
    float e = (seli[s] != r) ? __expf(selv[s] - m) : 0.f;
    wg[s] = e; den += e;
  }
  const float rden = 1.0f / den;

  float p0 = 0.f, p1 = 0.f;
#pragma unroll
  for (int s = 0; s < KP1; ++s) {
    const float* pr = proj + (size_t)seli[s] * DD;
    float ws = wg[s] * rden;
    p0 += ws * pr[l];
    p1 += ws * pr[l + 64];
  }
  out[(size_t)r * DD + l] = feat[(size_t)r * DD + l] + 0.1f * (p0 + emb[l]);
  out[(size_t)r * DD + l + 64] =
      feat[(size_t)r * DD + l + 64] + 0.1f * (p1 + emb[l + 64]);
}

// ---------------------------------------------------------------------------
extern "C" void kernel_launch(void* const* d_in, const int* in_sizes, int n_in,
                              void* d_out, int out_size, void* d_ws, size_t ws_size,
                              hipStream_t stream) {
  (void)in_sizes; (void)n_in; (void)out_size; (void)ws_size;
  const float* feat = (const float*)d_in[0];
  const float* W    = (const float*)d_in[1];
  const float* emb  = (const float*)d_in[2];
  float* out = (float*)d_out;

  char* ws = (char*)d_ws;
  float* proj          = (float*)ws;                                    // 8 MB
  __hip_bfloat16* nrmb = (__hip_bfloat16*)(ws + (size_t)NN * DD * 4);   // 4 MB
  float* tkv = (float*)(ws + (size_t)NN * DD * 6);                      // 5.77 MB
  int*   tki = (int*)(ws + (size_t)NN * DD * 6 +
                      (size_t)NSPLIT * NN * KP1 * 4);                   // 5.77 MB

  phaseA_kernel<<<NN / 16, 256, 0, stream>>>(feat, W, proj, nrmb);
  phaseB_kernel<<<64 * NSPLIT, 256, 0, stream>>>(nrmb, tkv, tki);
  phaseC_kernel<<<NN / 4, 256, 0, stream>>>(proj, feat, emb, tkv, tki, out);
}

// Round 3
// 708.131 us; speedup vs baseline: 4.4659x; 4.4659x over previous
//
#include <hip/hip_runtime.h>
#include <hip/hip_bf16.h>

#define NN 16384
#define DD 128
#define KP1 11
#define NSPLIT 8
#define RBLK 256
#define CBLK 64
#define COLS_PER_SPLIT (NN / NSPLIT)   /* 2048 */
#define NITER (COLS_PER_SPLIT / CBLK)  /* 32 */

typedef __attribute__((ext_vector_type(8))) short bf16x8;
typedef __attribute__((ext_vector_type(4))) float f32x4;
typedef unsigned long long u64;
typedef unsigned int u32;

// ---------------------------------------------------------------------------
// Phase A: proj = feat @ W^T (fp32 exact), row L2 norm, bf16 normalized copy
// ---------------------------------------------------------------------------
__global__ __launch_bounds__(256) void phaseA_kernel(
    const float* __restrict__ feat, const float* __restrict__ W,
    float* __restrict__ proj, __hip_bfloat16* __restrict__ nrmb) {
  __shared__ float Wl[DD][132];
  __shared__ float fl[16][DD];
  const int t = threadIdx.x;
  const int blk = blockIdx.x;     // 16 rows per block

  const f32x4* W4 = (const f32x4*)W;
#pragma unroll
  for (int i = 0; i < 16; ++i) {
    int f4 = t + 256 * i;
    *(f32x4*)&Wl[f4 >> 5][(f4 & 31) * 4] = W4[f4];
  }
  const f32x4* F4 = (const f32x4*)(feat + (size_t)blk * 16 * DD);
#pragma unroll
  for (int i = 0; i < 2; ++i) {
    int f4 = t + 256 * i;
    *(f32x4*)&fl[f4 >> 5][(f4 & 31) * 4] = F4[f4];
  }
  __syncthreads();

  const int w = t >> 6, l = t & 63;
#pragma unroll 1
  for (int q = 0; q < 4; ++q) {
    const int rloc = w * 4 + q;
    const int r = blk * 16 + rloc;
    float a0 = 0.f, a1 = 0.f;
#pragma unroll
    for (int k = 0; k < DD; k += 4) {
      f32x4 fv = *(const f32x4*)&fl[rloc][k];
      f32x4 w0 = *(const f32x4*)&Wl[l][k];
      f32x4 w1 = *(const f32x4*)&Wl[l + 64][k];
      a0 += fv[0] * w0[0] + fv[1] * w0[1] + fv[2] * w0[2] + fv[3] * w0[3];
      a1 += fv[0] * w1[0] + fv[1] * w1[1] + fv[2] * w1[2] + fv[3] * w1[3];
    }
    float n2 = a0 * a0 + a1 * a1;
#pragma unroll
    for (int o = 32; o > 0; o >>= 1) n2 += __shfl_xor(n2, o);
    float invn = 1.0f / fmaxf(sqrtf(n2), 1e-12f);
    proj[(size_t)r * DD + l] = a0;
    proj[(size_t)r * DD + l + 64] = a1;
    nrmb[(size_t)r * DD + l] = __float2bfloat16(a0 * invn);
    nrmb[(size_t)r * DD + l + 64] = __float2bfloat16(a1 * invn);
  }
}

// ---------------------------------------------------------------------------
// Phase B: tiled Gram matrix via bf16 MFMA + fused per-row top-11.
// Top-11 ladder = 11 NAMED u64 registers (no arrays -> no scratch, rule #20).
// Key = (order-preserving f32 bits << 32) | (16383 - idx): one u64 compare
// gives (val desc, idx asc) ordering == jax.lax.top_k tie semantics.
// B fragments load straight from global (L2-resident), LDS = Sm only
// -> 2 blocks/CU, whole 512-block grid co-resident.
// ---------------------------------------------------------------------------
#define LSTEP(kj) { bool g_ = ck > (kj); u64 t_ = g_ ? ck : (kj); \
                    ck = g_ ? (kj) : ck; (kj) = t_; }

__global__ __launch_bounds__(256, 2) void phaseB_kernel(
    const __hip_bfloat16* __restrict__ nrmb,
    float* __restrict__ tkv, int* __restrict__ tki) {
  __shared__ float Sm[RBLK][68];            // 69632 B; 2 blocks/CU
  const int t = threadIdx.x;
  const int w = t >> 6, l = t & 63;
  const int rb = blockIdx.x & 63;
  const int cs = blockIdx.x >> 6;
  const int row0 = rb * RBLK;
  const int wrow = row0 + w * 64;
  const int lr = l & 15, lg = l >> 4;
  const unsigned short* nb = (const unsigned short*)nrmb;

  // A fragments (my 64 rows per wave), held in registers all kernel
  bf16x8 A[4][4];
#pragma unroll
  for (int rt = 0; rt < 4; ++rt)
#pragma unroll
    for (int kt = 0; kt < 4; ++kt)
      A[rt][kt] = *(const bf16x8*)(nb + (size_t)(wrow + rt * 16 + lr) * DD +
                                   kt * 32 + lg * 8);

  // top-11 ladder, descending: k0 >= k1 >= ... >= k10
  u64 k0 = 0, k1 = 0, k2 = 0, k3 = 0, k4 = 0, k5 = 0,
      k6 = 0, k7 = 0, k8 = 0, k9 = 0, k10 = 0;

  const int csbase = cs * COLS_PER_SPLIT;

  for (int it = 0; it < NITER; ++it) {
    // issue B-fragment loads for this tile (overlap with the scan below)
    bf16x8 Bf[4][4];
#pragma unroll
    for (int ct2 = 0; ct2 < 4; ++ct2)
#pragma unroll
      for (int kt = 0; kt < 4; ++kt)
        Bf[ct2][kt] = *(const bf16x8*)(
            nb + (size_t)(csbase + it * CBLK + ct2 * 16 + lr) * DD +
            kt * 32 + lg * 8);

    // scan previous sims tile (thread t owns row row0+t)
    if (it > 0) {
      const int cprev = csbase + (it - 1) * CBLK;
#pragma unroll 1
      for (int j4 = 0; j4 < 16; ++j4) {
        f32x4 v = *(const f32x4*)&Sm[t][j4 * 4];
#pragma unroll
        for (int u = 0; u < 4; ++u) {
          u32 b = __float_as_uint(v[u]);
          u32 fk = b ^ (u32)(((int)b >> 31) | 0x80000000);
          u64 ck = ((u64)fk << 32) | (u32)(16383 - (cprev + j4 * 4 + u));
          if (ck > k10) {
            LSTEP(k0) LSTEP(k1) LSTEP(k2) LSTEP(k3) LSTEP(k4) LSTEP(k5)
            LSTEP(k6) LSTEP(k7) LSTEP(k8) LSTEP(k9) LSTEP(k10)
          }
        }
      }
    }
    __syncthreads();
    // MFMA: 64x64 sims per wave, write to LDS in C/D layout
#pragma unroll
    for (int ct2 = 0; ct2 < 4; ++ct2) {
      f32x4 acc[4];
#pragma unroll
      for (int rt = 0; rt < 4; ++rt) acc[rt] = (f32x4){0.f, 0.f, 0.f, 0.f};
#pragma unroll
      for (int kt = 0; kt < 4; ++kt)
#pragma unroll
        for (int rt = 0; rt < 4; ++rt)
          acc[rt] = __builtin_amdgcn_mfma_f32_16x16x32_bf16(
              A[rt][kt], Bf[ct2][kt], acc[rt], 0, 0, 0);
#pragma unroll
      for (int rt = 0; rt < 4; ++rt)
#pragma unroll
        for (int i = 0; i < 4; ++i)
          Sm[w * 64 + rt * 16 + lg * 4 + i][ct2 * 16 + lr] = acc[rt][i];
    }
    __syncthreads();
  }
  // final tile scan
  {
    const int cprev = csbase + (NITER - 1) * CBLK;
#pragma unroll 1
    for (int j4 = 0; j4 < 16; ++j4) {
      f32x4 v = *(const f32x4*)&Sm[t][j4 * 4];
#pragma unroll
      for (int u = 0; u < 4; ++u) {
        u32 b = __float_as_uint(v[u]);
        u32 fk = b ^ (u32)(((int)b >> 31) | 0x80000000);
        u64 ck = ((u64)fk << 32) | (u32)(16383 - (cprev + j4 * 4 + u));
        if (ck > k10) {
          LSTEP(k0) LSTEP(k1) LSTEP(k2) LSTEP(k3) LSTEP(k4) LSTEP(k5)
          LSTEP(k6) LSTEP(k7) LSTEP(k8) LSTEP(k9) LSTEP(k10)
        }
      }
    }
  }
  // unpack + store (descending order; phase C is order-agnostic anyway)
  const int myrow = row0 + t;
  float* ov = tkv + ((size_t)cs * NN + myrow) * KP1;
  int* oi = tki + ((size_t)cs * NN + myrow) * KP1;
  u64 ks[KP1] = {k0, k1, k2, k3, k4, k5, k6, k7, k8, k9, k10};
#pragma unroll
  for (int i = 0; i < KP1; ++i) {
    u32 fk = (u32)(ks[i] >> 32);
    u32 b = fk ^ ((fk & 0x80000000u) ? 0x80000000u : 0xFFFFFFFFu);
    ov[i] = __uint_as_float(b);
    oi[i] = 16383 - (int)(ks[i] & 0xFFFFFFFFu);
  }
}

// ---------------------------------------------------------------------------
// Phase C: merge 8x11 partial top-k per row, softmax (self masked), gather
// one wave per row; 4 rows per 256-thread block. fp32 output.
// ---------------------------------------------------------------------------
__global__ __launch_bounds__(256) void phaseC_kernel(
    const float* __restrict__ proj, const float* __restrict__ feat,
    const float* __restrict__ emb, const float* __restrict__ tkv,
    const int* __restrict__ tki, float* __restrict__ out) {
  const int t = threadIdx.x, w = t >> 6, l = t & 63;
  const int r = blockIdx.x * 4 + w;

  float v0, v1 = -3.0e38f;
  int i0, i1 = 0x7fffffff;
  {
    int j = l, s = j / KP1, k = j - s * KP1;
    v0 = tkv[((size_t)s * NN + r) * KP1 + k];
    i0 = tki[((size_t)s * NN + r) * KP1 + k];
  }
  if (l < 88 - 64) {
    int j = 64 + l, s = j / KP1, k = j - s * KP1;
    v1 = tkv[((size_t)s * NN + r) * KP1 + k];
    i1 = tki[((size_t)s * NN + r) * KP1 + k];
  }

  bool t0 = false, t1 = false;
  float selv[KP1]; int seli[KP1];
#pragma unroll
  for (int s = 0; s < KP1; ++s) {
    float bv = -3.0e38f; int bi = 0x7fffffff;
    if (!t0 && (v0 > bv || (v0 == bv && i0 < bi))) { bv = v0; bi = i0; }
    if (!t1 && (v1 > bv || (v1 == bv && i1 < bi))) { bv = v1; bi = i1; }
#pragma unroll
    for (int o = 32; o > 0; o >>= 1) {
      float ovv = __shfl_xor(bv, o);
      int obi = __shfl_xor(bi, o);
      if (ovv > bv || (ovv == bv && obi < bi)) { bv = ovv; bi = obi; }
    }
    selv[s] = bv; seli[s] = bi;
    if (!t0 && i0 == bi) t0 = true;
    else if (!t1 && i1 == bi) t1 = true;
  }

  float m = -3.0e38f;
#pragma unroll
  for (int s = 0; s < KP1; ++s)
    if (seli[s] != r) m = fmaxf(m, selv[s]);
  float den = 0.f; float wg[KP1];
#pragma unroll
  for (int s = 0; s < KP1; ++s) {
    float e = (seli[s] != r) ? __expf(selv[s] - m) : 0.f;
    wg[s] = e; den += e;
  }
  const float rden = 1.0f / den;

  float p0 = 0.f, p1 = 0.f;
#pragma unroll
  for (int s = 0; s < KP1; ++s) {
    const float* pr = proj + (size_t)seli[s] * DD;
    float ws = wg[s] * rden;
    p0 += ws * pr[l];
    p1 += ws * pr[l + 64];
  }
  out[(size_t)r * DD + l] = feat[(size_t)r * DD + l] + 0.1f * (p0 + emb[l]);
  out[(size_t)r * DD + l + 64] =
      feat[(size_t)r * DD + l + 64] + 0.1f * (p1 + emb[l + 64]);
}

// ---------------------------------------------------------------------------
extern "C" void kernel_launch(void* const* d_in, const int* in_sizes, int n_in,
                              void* d_out, int out_size, void* d_ws, size_t ws_size,
                              hipStream_t stream) {
  (void)in_sizes; (void)n_in; (void)out_size; (void)ws_size;
  const float* feat = (const float*)d_in[0];
  const float* W    = (const float*)d_in[1];
  const float* emb  = (const float*)d_in[2];
  float* out = (float*)d_out;

  char* ws = (char*)d_ws;
  float* proj          = (float*)ws;                                    // 8 MB
  __hip_bfloat16* nrmb = (__hip_bfloat16*)(ws + (size_t)NN * DD * 4);   // 4 MB
  float* tkv = (float*)(ws + (size_t)NN * DD * 6);                      // 5.77 MB
  int*   tki = (int*)(ws + (size_t)NN * DD * 6 +
                      (size_t)NSPLIT * NN * KP1 * 4);                   // 5.77 MB

  phaseA_kernel<<<NN / 16, 256, 0, stream>>>(feat, W, proj, nrmb);
  phaseB_kernel<<<64 * NSPLIT, 256, 0, stream>>>(nrmb, tkv, tki);
  phaseC_kernel<<<NN / 4, 256, 0, stream>>>(proj, feat, emb, tkv, tki, out);
}

// Round 4
// 385.300 us; speedup vs baseline: 8.2078x; 1.8379x over previous
//
#include <hip/hip_runtime.h>
#include <hip/hip_bf16.h>

#define NN 16384
#define DD 128
#define KP1 11
#define NSPLIT 8
#define RBLK 256
#define CBLK 64
#define COLS_PER_SPLIT (NN / NSPLIT)   /* 2048 */
#define NITER (COLS_PER_SPLIT / CBLK)  /* 32 */
#define SDEPTH 4

typedef __attribute__((ext_vector_type(8))) short bf16x8;
typedef __attribute__((ext_vector_type(4))) float f32x4;
typedef unsigned long long u64;
typedef unsigned int u32;

// ---------------------------------------------------------------------------
// Phase A: proj = feat @ W^T (fp32 exact), row L2 norm, bf16 normalized copy
// ---------------------------------------------------------------------------
__global__ __launch_bounds__(256) void phaseA_kernel(
    const float* __restrict__ feat, const float* __restrict__ W,
    float* __restrict__ proj, __hip_bfloat16* __restrict__ nrmb) {
  __shared__ float Wl[DD][132];
  __shared__ float fl[16][DD];
  const int t = threadIdx.x;
  const int blk = blockIdx.x;     // 16 rows per block

  const f32x4* W4 = (const f32x4*)W;
#pragma unroll
  for (int i = 0; i < 16; ++i) {
    int f4 = t + 256 * i;
    *(f32x4*)&Wl[f4 >> 5][(f4 & 31) * 4] = W4[f4];
  }
  const f32x4* F4 = (const f32x4*)(feat + (size_t)blk * 16 * DD);
#pragma unroll
  for (int i = 0; i < 2; ++i) {
    int f4 = t + 256 * i;
    *(f32x4*)&fl[f4 >> 5][(f4 & 31) * 4] = F4[f4];
  }
  __syncthreads();

  const int w = t >> 6, l = t & 63;
#pragma unroll 1
  for (int q = 0; q < 4; ++q) {
    const int rloc = w * 4 + q;
    const int r = blk * 16 + rloc;
    float a0 = 0.f, a1 = 0.f;
#pragma unroll
    for (int k = 0; k < DD; k += 4) {
      f32x4 fv = *(const f32x4*)&fl[rloc][k];
      f32x4 w0 = *(const f32x4*)&Wl[l][k];
      f32x4 w1 = *(const f32x4*)&Wl[l + 64][k];
      a0 += fv[0] * w0[0] + fv[1] * w0[1] + fv[2] * w0[2] + fv[3] * w0[3];
      a1 += fv[0] * w1[0] + fv[1] * w1[1] + fv[2] * w1[2] + fv[3] * w1[3];
    }
    float n2 = a0 * a0 + a1 * a1;
#pragma unroll
    for (int o = 32; o > 0; o >>= 1) n2 += __shfl_xor(n2, o);
    float invn = 1.0f / fmaxf(sqrtf(n2), 1e-12f);
    proj[(size_t)r * DD + l] = a0;
    proj[(size_t)r * DD + l + 64] = a1;
    nrmb[(size_t)r * DD + l] = __float2bfloat16(a0 * invn);
    nrmb[(size_t)r * DD + l + 64] = __float2bfloat16(a1 * invn);
  }
}

// ---------------------------------------------------------------------------
// Phase B: tiled Gram matrix via bf16 MFMA + fused per-row top-11.
// Ladder = 11 named u64 regs. Scan = f32 threshold pre-filter -> LDS survivor
// stack (depth 4) -> per-tile batched drain (depth-synchronized across lanes,
// cutting wave-level ladder runs ~10x vs inline insert).
// Key = (order-preserving f32 bits << 32) | (16383 - idx)  => one u64 compare
// gives (val desc, idx asc) == jax.lax.top_k tie semantics. Push uses >= so
// equal-value/smaller-idx candidates are kept.
// ---------------------------------------------------------------------------
#define LSTEP(kj) { bool g_ = ck > (kj); u64 t_ = g_ ? ck : (kj); \
                    ck = g_ ? (kj) : ck; (kj) = t_; }
#define LADDER11 { LSTEP(k0) LSTEP(k1) LSTEP(k2) LSTEP(k3) LSTEP(k4) \
                   LSTEP(k5) LSTEP(k6) LSTEP(k7) LSTEP(k8) LSTEP(k9) LSTEP(k10) }

#define SCAN_TILE(cprev_)                                                     \
  {                                                                           \
    const int cprev = (cprev_);                                               \
    _Pragma("unroll 4")                                                       \
    for (int j4 = 0; j4 < 16; ++j4) {                                         \
      f32x4 v = *(const f32x4*)&Sm[t][j4 * 4];                                \
      _Pragma("unroll")                                                       \
      for (int u = 0; u < 4; ++u) {                                           \
        float vv = v[u];                                                      \
        if (vv >= thrv) {                                                     \
          u32 b = __float_as_uint(vv);                                        \
          u32 fk = b ^ (u32)(((int)b >> 31) | 0x80000000);                    \
          u64 ck = ((u64)fk << 32) | (u32)(16383 - (cprev + j4 * 4 + u));     \
          if (cnt < SDEPTH) {                                                 \
            StkL[cnt * 256 + t] = ck;                                         \
            ++cnt;                                                            \
          } else {                                                            \
            LADDER11                                                          \
          }                                                                   \
        }                                                                     \
      }                                                                       \
    }                                                                         \
    while (__any(cnt > 0)) {                                                  \
      u64 ck = 0;                                                             \
      if (cnt > 0) { --cnt; ck = StkL[cnt * 256 + t]; }                       \
      LADDER11                                                                \
    }                                                                         \
    u32 fk10 = (u32)(k10 >> 32);                                              \
    thrv = (fk10 == 0u)                                                       \
               ? -3.0e38f                                                     \
               : __uint_as_float(fk10 ^ ((fk10 & 0x80000000u) ? 0x80000000u   \
                                                             : 0xFFFFFFFFu)); \
  }

__global__ __launch_bounds__(256, 2) void phaseB_kernel(
    const __hip_bfloat16* __restrict__ nrmb,
    float* __restrict__ tkv, int* __restrict__ tki) {
  __shared__ float Sm[RBLK][68];        // 69632 B
  __shared__ u64 StkL[SDEPTH * 256];    // 8192 B -> total 77824, 2 blocks/CU
  const int t = threadIdx.x;
  const int w = t >> 6, l = t & 63;
  const int rb = blockIdx.x & 63;
  const int cs = blockIdx.x >> 6;
  const int row0 = rb * RBLK;
  const int wrow = row0 + w * 64;
  const int lr = l & 15, lg = l >> 4;
  const unsigned short* nb = (const unsigned short*)nrmb;

  // A fragments (this wave's 64 rows), held in registers all kernel
  bf16x8 A[4][4];
#pragma unroll
  for (int rt = 0; rt < 4; ++rt)
#pragma unroll
    for (int kt = 0; kt < 4; ++kt)
      A[rt][kt] = *(const bf16x8*)(nb + (size_t)(wrow + rt * 16 + lr) * DD +
                                   kt * 32 + lg * 8);

  // top-11 ladder, descending: k0 >= k1 >= ... >= k10
  u64 k0 = 0, k1 = 0, k2 = 0, k3 = 0, k4 = 0, k5 = 0,
      k6 = 0, k7 = 0, k8 = 0, k9 = 0, k10 = 0;
  float thrv = -3.0e38f;  // f32 value of current 11th-best
  int cnt = 0;            // survivor-stack depth

  const int csbase = cs * COLS_PER_SPLIT;

  for (int it = 0; it < NITER; ++it) {
    // issue B-fragment loads for this tile (overlap with the scan below)
    bf16x8 Bf[4][4];
#pragma unroll
    for (int ct2 = 0; ct2 < 4; ++ct2)
#pragma unroll
      for (int kt = 0; kt < 4; ++kt)
        Bf[ct2][kt] = *(const bf16x8*)(
            nb + (size_t)(csbase + it * CBLK + ct2 * 16 + lr) * DD +
            kt * 32 + lg * 8);

    // scan previous sims tile (thread t owns row row0+t)
    if (it > 0) SCAN_TILE(csbase + (it - 1) * CBLK);
    __syncthreads();
    // MFMA: 64x64 sims per wave, write to LDS in C/D layout
#pragma unroll
    for (int ct2 = 0; ct2 < 4; ++ct2) {
      f32x4 acc[4];
#pragma unroll
      for (int rt = 0; rt < 4; ++rt) acc[rt] = (f32x4){0.f, 0.f, 0.f, 0.f};
#pragma unroll
      for (int kt = 0; kt < 4; ++kt)
#pragma unroll
        for (int rt = 0; rt < 4; ++rt)
          acc[rt] = __builtin_amdgcn_mfma_f32_16x16x32_bf16(
              A[rt][kt], Bf[ct2][kt], acc[rt], 0, 0, 0);
#pragma unroll
      for (int rt = 0; rt < 4; ++rt)
#pragma unroll
        for (int i = 0; i < 4; ++i)
          Sm[w * 64 + rt * 16 + lg * 4 + i][ct2 * 16 + lr] = acc[rt][i];
    }
    __syncthreads();
  }
  // final tile scan
  SCAN_TILE(csbase + (NITER - 1) * CBLK);

  // unpack + store (descending order; phase C is order-agnostic anyway)
  const int myrow = row0 + t;
  float* ov = tkv + ((size_t)cs * NN + myrow) * KP1;
  int* oi = tki + ((size_t)cs * NN + myrow) * KP1;
  u64 ks[KP1] = {k0, k1, k2, k3, k4, k5, k6, k7, k8, k9, k10};
#pragma unroll
  for (int i = 0; i < KP1; ++i) {
    u32 fk = (u32)(ks[i] >> 32);
    u32 b = fk ^ ((fk & 0x80000000u) ? 0x80000000u : 0xFFFFFFFFu);
    ov[i] = __uint_as_float(b);
    oi[i] = 16383 - (int)(ks[i] & 0xFFFFFFFFu);
  }
}

// ---------------------------------------------------------------------------
// Phase C: merge 8x11 partial top-k per row, softmax (self masked), gather
// one wave per row; 4 rows per 256-thread block. fp32 output.
// ---------------------------------------------------------------------------
__global__ __launch_bounds__(256) void phaseC_kernel(
    const float* __restrict__ proj, const float* __restrict__ feat,
    const float* __restrict__ emb, const float* __restrict__ tkv,
    const int* __restrict__ tki, float* __restrict__ out) {
  const int t = threadIdx.x, w = t >> 6, l = t & 63;
  const int r = blockIdx.x * 4 + w;

  float v0, v1 = -3.0e38f;
  int i0, i1 = 0x7fffffff;
  {
    int j = l, s = j / KP1, k = j - s * KP1;
    v0 = tkv[((size_t)s * NN + r) * KP1 + k];
    i0 = tki[((size_t)s * NN + r) * KP1 + k];
  }
  if (l < 88 - 64) {
    int j = 64 + l, s = j / KP1, k = j - s * KP1;
    v1 = tkv[((size_t)s * NN + r) * KP1 + k];
    i1 = tki[((size_t)s * NN + r) * KP1 + k];
  }

  bool t0 = false, t1 = false;
  float selv[KP1]; int seli[KP1];
#pragma unroll
  for (int s = 0; s < KP1; ++s) {
    float bv = -3.0e38f; int bi = 0x7fffffff;
    if (!t0 && (v0 > bv || (v0 == bv && i0 < bi))) { bv = v0; bi = i0; }
    if (!t1 && (v1 > bv || (v1 == bv && i1 < bi))) { bv = v1; bi = i1; }
#pragma unroll
    for (int o = 32; o > 0; o >>= 1) {
      float ovv = __shfl_xor(bv, o);
      int obi = __shfl_xor(bi, o);
      if (ovv > bv || (ovv == bv && obi < bi)) { bv = ovv; bi = obi; }
    }
    selv[s] = bv; seli[s] = bi;
    if (!t0 && i0 == bi) t0 = true;
    else if (!t1 && i1 == bi) t1 = true;
  }

  float m = -3.0e38f;
#pragma unroll
  for (int s = 0; s < KP1; ++s)
    if (seli[s] != r) m = fmaxf(m, selv[s]);
  float den = 0.f; float wg[KP1];
#pragma unroll
  for (int s = 0; s < KP1; ++s) {
    float e = (seli[s] != r) ? __expf(selv[s] - m) : 0.f;
    wg[s] = e; den += e;
  }
  const float rden = 1.0f / den;

  float p0 = 0.f, p1 = 0.f;
#pragma unroll
  for (int s = 0; s < KP1; ++s) {
    const float* pr = proj + (size_t)seli[s] * DD;
    float ws = wg[s] * rden;
    p0 += ws * pr[l];
    p1 += ws * pr[l + 64];
  }
  out[(size_t)r * DD + l] = feat[(size_t)r * DD + l] + 0.1f * (p0 + emb[l]);
  out[(size_t)r * DD + l + 64] =
      feat[(size_t)r * DD + l + 64] + 0.1f * (p1 + emb[l + 64]);
}

// ---------------------------------------------------------------------------
extern "C" void kernel_launch(void* const* d_in, const int* in_sizes, int n_in,
                              void* d_out, int out_size, void* d_ws, size_t ws_size,
                              hipStream_t stream) {
  (void)in_sizes; (void)n_in; (void)out_size; (void)ws_size;
  const float* feat = (const float*)d_in[0];
  const float* W    = (const float*)d_in[1];
  const float* emb  = (const float*)d_in[2];
  float* out = (float*)d_out;

  char* ws = (char*)d_ws;
  float* proj          = (float*)ws;                                    // 8 MB
  __hip_bfloat16* nrmb = (__hip_bfloat16*)(ws + (size_t)NN * DD * 4);   // 4 MB
  float* tkv = (float*)(ws + (size_t)NN * DD * 6);                      // 5.77 MB
  int*   tki = (int*)(ws + (size_t)NN * DD * 6 +
                      (size_t)NSPLIT * NN * KP1 * 4);                   // 5.77 MB

  phaseA_kernel<<<NN / 16, 256, 0, stream>>>(feat, W, proj, nrmb);
  phaseB_kernel<<<64 * NSPLIT, 256, 0, stream>>>(nrmb, tkv, tki);
  phaseC_kernel<<<NN / 4, 256, 0, stream>>>(proj, feat, emb, tkv, tki, out);
}